// Round 5
// baseline (895.864 us; speedup 1.0000x reference)
//
#include <hip/hip_runtime.h>

typedef __attribute__((ext_vector_type(8))) short short8;
typedef __attribute__((ext_vector_type(4))) float f32x4;

#define NPB   128                 // nodes per bucket
#define CAPB  2688                // max edges per bucket (mean 2046)
#define TILE  8192                // edges per tile-sort block
#define MAXB  800                 // max buckets (N <= 102400)

__device__ __forceinline__ float bf2f(unsigned short u){
  union { float f; unsigned u; } v; v.u = ((unsigned)u) << 16; return v.f;
}
__device__ __forceinline__ unsigned short f2bf(float f){
  union { float f; unsigned u; } v; v.f = f;
  unsigned r = v.u + 0x7fffu + ((v.u >> 16) & 1u);
  return (unsigned short)(r >> 16);
}

// ---- edge dtype detection: int64 edge_index has odd 32-bit words == 0 ----
__global__ void k_detect(const unsigned* ei, int* flag){
  unsigned v = ei[2*threadIdx.x + 1];
  unsigned long long any = __ballot(v != 0u);
  if (threadIdx.x == 0) flag[0] = (any == 0ull) ? 1 : 0;   // 1 => int64
}

// ---- phase 1: per-block tile sort -> dense bulk append into buckets ----
__global__ __launch_bounds__(256) void k_bucket2(const void* ei, const int* __restrict__ flag,
    int* __restrict__ bcnt, unsigned* __restrict__ buf, int E, int nbuck)
{
  __shared__ unsigned recs[TILE];
  __shared__ unsigned short recb[TILE];
  __shared__ int cnt[MAXB];
  __shared__ int offs[MAXB];
  __shared__ int ofc[MAXB];
  __shared__ int gbase[MAXB];
  __shared__ int sc[256];

  const int tid = threadIdx.x;
  const bool i64 = flag[0] != 0;
  const int e0 = blockIdx.x * TILE;
  const int m = min(TILE, E - e0);
  if (m <= 0) return;

  for (int i = tid; i < nbuck; i += 256) cnt[i] = 0;
  __syncthreads();

  for (int i = tid; i < m; i += 256){
    int c = i64 ? (int)((const long long*)ei)[(size_t)E + e0 + i]
                : ((const int*)ei)[(size_t)E + e0 + i];
    atomicAdd(&cnt[c >> 7], 1);
  }
  __syncthreads();

  int lc[4]; int tsum = 0;
#pragma unroll
  for (int j = 0; j < 4; ++j){
    int b = tid*4 + j;
    lc[j] = (b < nbuck) ? cnt[b] : 0;
    tsum += lc[j];
  }
  sc[tid] = tsum; __syncthreads();
  for (int off = 1; off < 256; off <<= 1){
    int a = (tid >= off) ? sc[tid - off] : 0;
    __syncthreads(); sc[tid] += a; __syncthreads();
  }
  int run = sc[tid] - tsum;
#pragma unroll
  for (int j = 0; j < 4; ++j){
    int b = tid*4 + j;
    if (b < nbuck){
      offs[b] = run; ofc[b] = run;
      gbase[b] = lc[j] ? atomicAdd(&bcnt[b*16], lc[j]) : 0;
    }
    run += lc[j];
  }
  __syncthreads();

  for (int i = tid; i < m; i += 256){
    int r, c;
    if (i64){ const long long* p = (const long long*)ei; r = (int)p[e0+i]; c = (int)p[(size_t)E+e0+i]; }
    else    { const int* p = (const int*)ei;            r = p[e0+i];      c = p[(size_t)E+e0+i]; }
    int b = c >> 7;
    int pos = atomicAdd(&ofc[b], 1);
    recs[pos] = ((unsigned)(c & (NPB-1)) << 17) | (unsigned)r;
    recb[pos] = (unsigned short)b;
  }
  __syncthreads();

  for (int i = tid; i < m; i += 256){
    int b = recb[i];
    int dst = gbase[b] + (i - offs[b]);
    if (dst < CAPB) buf[(size_t)b*CAPB + dst] = recs[i];
  }
}

// ---- phase 2: exclusive scan of bucket sizes (<=1024 buckets) ----
__global__ void k_bscan(const int* __restrict__ bcnt, int* __restrict__ bbase,
                        int* __restrict__ indptr, int nbuck, int N, int E){
  __shared__ int s[1024];
  const int tid = threadIdx.x;
  int v = (tid < nbuck) ? min(bcnt[tid*16], CAPB) : 0;
  s[tid] = v; __syncthreads();
  for (int off = 1; off < 1024; off <<= 1){
    int a = (tid >= off) ? s[tid - off] : 0;
    __syncthreads();
    s[tid] += a;
    __syncthreads();
  }
  if (tid < nbuck) bbase[tid] = s[tid] - v;
  if (tid == 0) indptr[N] = E;
}

// ---- phase 3: per-bucket CSR build, all in LDS, no global atomics ----
__global__ __launch_bounds__(256) void k_csr(const int* __restrict__ bcnt,
    const int* __restrict__ bbase, const unsigned* __restrict__ buf,
    int* __restrict__ indptr, int* __restrict__ srcl, float* __restrict__ dinv, int N){
  __shared__ unsigned recs[CAPB];
  __shared__ int cnt[NPB];
  __shared__ int ex[NPB];
  __shared__ int sc[256];
  const int b = blockIdx.x, tid = threadIdx.x;
  const int m = min(bcnt[b*16], CAPB);
  const int base = bbase[b];

  if (tid < NPB) cnt[tid] = 0;
  __syncthreads();
  for (int i = tid; i < m; i += 256){
    unsigned rec = buf[(size_t)b*CAPB + i];
    recs[i] = rec;
    atomicAdd(&cnt[rec >> 17], 1);
  }
  __syncthreads();
  int v = (tid < NPB) ? cnt[tid] : 0;
  sc[tid] = v; __syncthreads();
  for (int off = 1; off < 256; off <<= 1){
    int a = (tid >= off) ? sc[tid - off] : 0;
    __syncthreads();
    sc[tid] += a;
    __syncthreads();
  }
  if (tid < NPB){
    int excl = sc[tid] - v;
    ex[tid] = excl;
    int g = b*NPB + tid;
    if (g < N){
      indptr[g] = base + excl;
      dinv[g]   = rsqrtf((float)v + 1.0f);    // +1 self-loop
    }
  }
  __syncthreads();
  for (int i = tid; i < m; i += 256){
    unsigned rec = recs[i];
    int pos = base + atomicAdd(&ex[rec >> 17], 1);
    srcl[pos] = (int)(rec & 0x1FFFFu);
  }
}

// ---- pre-pack ALL weights into MFMA B-fragment order, bf16, one dispatch ----
__global__ void k_wprep_all(const float* __restrict__ W_in, const float* __restrict__ convW,
                            const float* __restrict__ W_out, unsigned short* __restrict__ Bf){
  const int slot = blockIdx.x >> 3;
  const int idx  = (blockIdx.x & 7)*256 + threadIdx.x;
  const float* W; int ncol;
  if (slot == 0){ W = W_in; ncol = 128; }
  else if (slot <= 3){ W = convW + (size_t)(slot-1)*128*128; ncol = 128; }
  else { W = W_out; ncol = 64; }
  const int l = idx & 63, ks = (idx >> 6) & 3, cb = idx >> 8;
  if (cb >= (ncol >> 4)) return;
  const int c  = cb*16 + (l & 15);
  const int k0 = ks*32 + ((l >> 4) << 3);
  unsigned short* o = Bf + (size_t)slot*16384 + (size_t)idx*8;
#pragma unroll
  for (int j = 0; j < 8; ++j) o[j] = f2bf(W[(size_t)(k0 + j)*ncol + c]);
}

// ---- GEMM: [nrows,128] @ [128,NCOL]; 128-row tile/block, 4 waves x 32 rows ----
// TBLOCK: write bf16 out in group-blocked layout t[g=cb][row][16]
template<int NCOL, bool A_F32, bool BIAS, bool RELU, bool SCALE, bool OUT_F32, bool TBLOCK>
__global__ __launch_bounds__(256) void k_mm(const void* __restrict__ Ap,
    const unsigned short* __restrict__ Bf, const float* __restrict__ bias,
    const float* __restrict__ dinv, void* __restrict__ Cp, int nrows)
{
  constexpr int NCB = NCOL/16;
  const int tid = threadIdx.x;
  const int wave = tid >> 6, l = tid & 63;
  const int lr = l & 15, lg = l >> 4;
  const int row0 = blockIdx.x*128 + wave*32;

  f32x4 acc[2][NCB];
#pragma unroll
  for (int i = 0; i < 2; ++i)
#pragma unroll
    for (int j = 0; j < NCB; ++j) acc[i][j] = f32x4{0.f, 0.f, 0.f, 0.f};

  const int r0 = row0 + lr, r1 = row0 + 16 + lr;
  const bool ok0 = r0 < nrows, ok1 = r1 < nrows;

#pragma unroll
  for (int ks = 0; ks < 4; ++ks){
    const int kbase = ks*32 + lg*8;
    short8 a0 = short8{0,0,0,0,0,0,0,0}, a1 = short8{0,0,0,0,0,0,0,0};
    if constexpr (A_F32){
      const float* A = (const float*)Ap;
      if (ok0){
        const float* p = A + (size_t)r0*128 + kbase;
        f32x4 x0 = *(const f32x4*)p, x1 = *(const f32x4*)(p + 4);
#pragma unroll
        for (int j = 0; j < 4; ++j){ a0[j] = (short)f2bf(x0[j]); a0[j+4] = (short)f2bf(x1[j]); }
      }
      if (ok1){
        const float* p = A + (size_t)r1*128 + kbase;
        f32x4 x0 = *(const f32x4*)p, x1 = *(const f32x4*)(p + 4);
#pragma unroll
        for (int j = 0; j < 4; ++j){ a1[j] = (short)f2bf(x0[j]); a1[j+4] = (short)f2bf(x1[j]); }
      }
    } else {
      const unsigned short* A = (const unsigned short*)Ap;
      if (ok0) a0 = *(const short8*)(A + (size_t)r0*128 + kbase);
      if (ok1) a1 = *(const short8*)(A + (size_t)r1*128 + kbase);
    }
#pragma unroll
    for (int cb = 0; cb < NCB; ++cb){
      short8 b = *(const short8*)(Bf + ((size_t)(cb*4 + ks)*64 + l)*8);
      acc[0][cb] = __builtin_amdgcn_mfma_f32_16x16x32_bf16(a0, b, acc[0][cb], 0, 0, 0);
      acc[1][cb] = __builtin_amdgcn_mfma_f32_16x16x32_bf16(a1, b, acc[1][cb], 0, 0, 0);
    }
  }

  // C/D layout: col = lane&15, row = (lane>>4)*4 + reg
#pragma unroll
  for (int rb = 0; rb < 2; ++rb){
#pragma unroll
    for (int j = 0; j < 4; ++j){
      const int r = row0 + rb*16 + lg*4 + j;
      if (r >= nrows) continue;
      const float dv = SCALE ? dinv[r] : 1.0f;
#pragma unroll
      for (int cb = 0; cb < NCB; ++cb){
        const int c = cb*16 + lr;
        float v = acc[rb][cb][j];
        if constexpr (BIAS) v += bias[c];
        if constexpr (RELU) v = fmaxf(v, 0.0f);
        if constexpr (SCALE) v *= dv;
        if constexpr (OUT_F32) ((float*)Cp)[(size_t)r*NCOL + c] = v;
        else if constexpr (TBLOCK)
          ((unsigned short*)Cp)[(size_t)cb*nrows*16 + (size_t)r*16 + lr] = f2bf(v);
        else ((unsigned short*)Cp)[(size_t)r*NCOL + c] = f2bf(v);
      }
    }
  }
}

// ---- aggregation, XCD-sliced: group g = blockIdx%8 pins a 3.2MB t-slice per XCD L2 ----
// lane = (edge slot e8 = l>>3, dim pair d = l&7); 8 edges in flight per load instr
__global__ __launch_bounds__(256) void k_agg_b(const unsigned* __restrict__ tb,
    const int* __restrict__ indptr, const int* __restrict__ srcl,
    const float* __restrict__ dinv, const float* __restrict__ bias,
    unsigned* __restrict__ hout, int n)
{
  const int g = blockIdx.x & 7;
  const int node = (blockIdx.x >> 3)*4 + (threadIdx.x >> 6);
  if (node >= n) return;
  const int l = threadIdx.x & 63;
  const int e8 = l >> 3, d = l & 7;
  const unsigned* tg = tb + (size_t)g*n*8;

  float a0 = 0.f, a1 = 0.f;
  if (e8 == 0){                                   // self-loop term, counted once
    unsigned u = tg[(size_t)node*8 + d];
    a0 = bf2f((unsigned short)u); a1 = bf2f((unsigned short)(u >> 16));
  }

  int i = indptr[node];
  const int e = indptr[node + 1];
  for (; i + 32 <= e; i += 32){                   // 4 gathers in flight / lane
    int s0 = srcl[i      + e8], s1 = srcl[i + 8  + e8];
    int s2 = srcl[i + 16 + e8], s3 = srcl[i + 24 + e8];
    unsigned u0 = tg[(size_t)s0*8 + d], u1 = tg[(size_t)s1*8 + d];
    unsigned u2 = tg[(size_t)s2*8 + d], u3 = tg[(size_t)s3*8 + d];
    a0 += bf2f((unsigned short)u0) + bf2f((unsigned short)u1)
        + bf2f((unsigned short)u2) + bf2f((unsigned short)u3);
    a1 += bf2f((unsigned short)(u0 >> 16)) + bf2f((unsigned short)(u1 >> 16))
        + bf2f((unsigned short)(u2 >> 16)) + bf2f((unsigned short)(u3 >> 16));
  }
  for (; i + 16 <= e; i += 16){
    int s0 = srcl[i + e8], s1 = srcl[i + 8 + e8];
    unsigned u0 = tg[(size_t)s0*8 + d], u1 = tg[(size_t)s1*8 + d];
    a0 += bf2f((unsigned short)u0) + bf2f((unsigned short)u1);
    a1 += bf2f((unsigned short)(u0 >> 16)) + bf2f((unsigned short)(u1 >> 16));
  }
  for (; i < e; i += 8){
    int j = i + e8;
    if (j < e){
      int s0 = srcl[j];
      unsigned u0 = tg[(size_t)s0*8 + d];
      a0 += bf2f((unsigned short)u0);
      a1 += bf2f((unsigned short)(u0 >> 16));
    }
  }

  // reduce over edge slots (lane bits 3,4,5)
  a0 += __shfl_xor(a0, 8);  a1 += __shfl_xor(a1, 8);
  a0 += __shfl_xor(a0, 16); a1 += __shfl_xor(a1, 16);
  a0 += __shfl_xor(a0, 32); a1 += __shfl_xor(a1, 32);

  if (e8 == 0){
    const float dv = dinv[node];
    float o0 = fmaxf(fmaf(dv, a0, bias[g*16 + 2*d]),     0.0f);
    float o1 = fmaxf(fmaf(dv, a1, bias[g*16 + 2*d + 1]), 0.0f);
    hout[(size_t)node*64 + g*8 + d] = (unsigned)f2bf(o0) | ((unsigned)f2bf(o1) << 16);
  }
}

extern "C" void kernel_launch(void* const* d_in, const int* in_sizes, int n_in,
                              void* d_out, int out_size, void* d_ws, size_t ws_size,
                              hipStream_t stream)
{
  const float* x     = (const float*)d_in[0];
  const void*  ei    = d_in[1];
  const float* W_in  = (const float*)d_in[2];
  const float* b_in  = (const float*)d_in[3];
  const float* convW = (const float*)d_in[4];
  const float* convb = (const float*)d_in[5];
  const float* W_out = (const float*)d_in[6];
  const float* b_out = (const float*)d_in[7];
  float* out = (float*)d_out;

  const int N = in_sizes[0] / 128;
  const int E = in_sizes[1] / 2;
  const int NBUCK = (N + NPB - 1) / NPB;

  char* w = (char*)d_ws;
  auto alloc = [&](size_t b){ char* p = w; w += (b + 255) & ~(size_t)255; return p; };
  unsigned short* h    = (unsigned short*)alloc((size_t)N*128*2);
  unsigned short* t    = (unsigned short*)alloc((size_t)N*128*2);   // group-blocked
  unsigned short* Bf   = (unsigned short*)alloc((size_t)5*16384*2);
  float* dinv          = (float*)alloc((size_t)N*4);
  int* indptr          = (int*)alloc((size_t)(N+1)*4);
  int* srcl            = (int*)alloc((size_t)E*4);
  int* bcnt            = (int*)alloc((size_t)NBUCK*64);
  int* bbase           = (int*)alloc((size_t)(NBUCK+1)*4);
  int* flag            = (int*)alloc(256);
  unsigned* bbuf       = (unsigned*)t;     // alias: bucket buffer dead before t is live

  const int MB = (N + 127) / 128;

  k_detect<<<1, 64, 0, stream>>>((const unsigned*)ei, flag);
  (void)hipMemsetAsync(bcnt, 0, (size_t)NBUCK*64, stream);
  k_wprep_all<<<40, 256, 0, stream>>>(W_in, convW, W_out, Bf);
  k_bucket2<<<(E + TILE - 1)/TILE, 256, 0, stream>>>(ei, flag, bcnt, bbuf, E, NBUCK);
  k_bscan <<<1, 1024, 0, stream>>>(bcnt, bbase, indptr, NBUCK, N, E);
  k_csr   <<<NBUCK, 256, 0, stream>>>(bcnt, bbase, bbuf, indptr, srcl, dinv, N);

  // h = relu(x @ W_in + b_in)
  k_mm<128, true, true, true, false, false, false><<<MB, 256, 0, stream>>>(x, Bf, b_in, nullptr, h, N);

  for (int L = 0; L < 3; ++L){
    // t[g][r][16] = dinv[r] * (h @ conv_W[L]), group-blocked
    k_mm<128, false, false, false, true, false, true><<<MB, 256, 0, stream>>>(h, Bf + (size_t)(1+L)*16384, nullptr, dinv, t, N);
    // h = relu(dinv[c] * (sum_in t + t[c]) + b), per-XCD feature slice
    k_agg_b<<<8*((N + 3)/4), 256, 0, stream>>>((const unsigned*)t, indptr, srcl, dinv,
                                               convb + (size_t)L*128, (unsigned*)h, N);
  }

  // logits = h @ W_out + b_out  (f32 out)
  k_mm<64, false, true, false, false, true, false><<<MB, 256, 0, stream>>>(h, Bf + (size_t)4*16384, b_out, nullptr, out, N);
}

// Round 6
// 345.313 us; speedup vs baseline: 2.5944x; 2.5944x over previous
//
#include <hip/hip_runtime.h>

typedef __attribute__((ext_vector_type(8))) short short8;
typedef __attribute__((ext_vector_type(4))) float f32x4;

#define NPB   128                 // nodes per bucket
#define CAPB  2688                // max edges per bucket (mean 2046)
#define TILE  8192                // edges per tile-sort block
#define MAXB  800                 // max buckets (N <= 102400)

__device__ __forceinline__ float bfLO(unsigned u){
  union { unsigned x; float f; } c; c.x = u << 16; return c.f;
}
__device__ __forceinline__ float bfHI(unsigned u){
  union { unsigned x; float f; } c; c.x = u & 0xffff0000u; return c.f;
}
__device__ __forceinline__ unsigned short f2bf(float f){
  union { float f; unsigned u; } v; v.f = f;
  unsigned r = v.u + 0x7fffu + ((v.u >> 16) & 1u);
  return (unsigned short)(r >> 16);
}

// ---- pre-pack ALL weights into MFMA B-fragment order + zero bcnt/cursor ----
__global__ void k_wprep_all(const float* __restrict__ W_in, const float* __restrict__ convW,
                            const float* __restrict__ W_out, unsigned short* __restrict__ Bf,
                            int* __restrict__ zeroPtr, int zeroN){
  if (blockIdx.x >= 40){                       // tail blocks: zero bcnt + cursor
    int i = (blockIdx.x - 40)*256 + threadIdx.x;
    if (i < zeroN) zeroPtr[i] = 0;
    return;
  }
  const int slot = blockIdx.x >> 3;
  const int idx  = (blockIdx.x & 7)*256 + threadIdx.x;
  const float* W; int ncol;
  if (slot == 0){ W = W_in; ncol = 128; }
  else if (slot <= 3){ W = convW + (size_t)(slot-1)*128*128; ncol = 128; }
  else { W = W_out; ncol = 64; }
  const int l = idx & 63, ks = (idx >> 6) & 3, cb = idx >> 8;
  if (cb >= (ncol >> 4)) return;
  const int c  = cb*16 + (l & 15);
  const int k0 = ks*32 + ((l >> 4) << 3);
  unsigned short* o = Bf + (size_t)slot*16384 + (size_t)idx*8;
#pragma unroll
  for (int j = 0; j < 8; ++j) o[j] = f2bf(W[(size_t)(k0 + j)*ncol + c]);
}

// ---- phase 1: per-block tile sort -> dense bulk append into buckets ----
// (int64-vs-int32 edge dtype detected per block: odd 32-bit words all zero => int64)
__global__ __launch_bounds__(256) void k_bucket2(const void* ei,
    int* __restrict__ bcnt, unsigned* __restrict__ buf, int E, int nbuck)
{
  __shared__ unsigned recs[TILE];
  __shared__ unsigned short recb[TILE];
  __shared__ int cnt[MAXB];
  __shared__ int offs[MAXB];
  __shared__ int ofc[MAXB];
  __shared__ int gbase[MAXB];
  __shared__ int sc[256];
  __shared__ int s_i64;

  const int tid = threadIdx.x;
  if (tid < 64){
    unsigned v = ((const unsigned*)ei)[2*tid + 1];
    unsigned long long any = __ballot(v != 0u);
    if (tid == 0) s_i64 = (any == 0ull) ? 1 : 0;
  }
  const int e0 = blockIdx.x * TILE;
  const int m = min(TILE, E - e0);
  if (m <= 0) return;

  for (int i = tid; i < nbuck; i += 256) cnt[i] = 0;
  __syncthreads();
  const bool i64 = s_i64 != 0;

  // A: histogram of targets
  for (int i = tid; i < m; i += 256){
    int c = i64 ? (int)((const long long*)ei)[(size_t)E + e0 + i]
                : ((const int*)ei)[(size_t)E + e0 + i];
    atomicAdd(&cnt[c >> 7], 1);
  }
  __syncthreads();

  // B: exclusive scan over buckets + reserve global ranges
  int lc[4]; int tsum = 0;
#pragma unroll
  for (int j = 0; j < 4; ++j){
    int b = tid*4 + j;
    lc[j] = (b < nbuck) ? cnt[b] : 0;
    tsum += lc[j];
  }
  sc[tid] = tsum; __syncthreads();
  for (int off = 1; off < 256; off <<= 1){
    int a = (tid >= off) ? sc[tid - off] : 0;
    __syncthreads(); sc[tid] += a; __syncthreads();
  }
  int run = sc[tid] - tsum;
#pragma unroll
  for (int j = 0; j < 4; ++j){
    int b = tid*4 + j;
    if (b < nbuck){
      offs[b] = run; ofc[b] = run;
      gbase[b] = lc[j] ? atomicAdd(&bcnt[b*16], lc[j]) : 0;
    }
    run += lc[j];
  }
  __syncthreads();

  // C: scatter records into grouped LDS array
  for (int i = tid; i < m; i += 256){
    int r, c;
    if (i64){ const long long* p = (const long long*)ei; r = (int)p[e0+i]; c = (int)p[(size_t)E+e0+i]; }
    else    { const int* p = (const int*)ei;            r = p[e0+i];      c = p[(size_t)E+e0+i]; }
    int b = c >> 7;
    int pos = atomicAdd(&ofc[b], 1);
    recs[pos] = ((unsigned)(c & (NPB-1)) << 17) | (unsigned)r;
    recb[pos] = (unsigned short)b;
  }
  __syncthreads();

  // D: dense copy-out
  for (int i = tid; i < m; i += 256){
    int b = recb[i];
    int dst = gbase[b] + (i - offs[b]);
    if (dst < CAPB) buf[(size_t)b*CAPB + dst] = recs[i];
  }
}

// ---- phase 2: per-bucket CSR build; span reserved via global cursor ----
__global__ __launch_bounds__(256) void k_csr2(const int* __restrict__ bcnt,
    const unsigned* __restrict__ buf, int2* __restrict__ nspan,
    int* __restrict__ srcl, float* __restrict__ dinv, int* __restrict__ cursor, int N){
  __shared__ unsigned recs[CAPB];
  __shared__ int cnt[NPB];
  __shared__ int ex[NPB];
  __shared__ int sc[256];
  __shared__ int s_base;
  const int b = blockIdx.x, tid = threadIdx.x;
  const int m = min(bcnt[b*16], CAPB);
  if (tid == 0) s_base = atomicAdd(cursor, m);

  if (tid < NPB) cnt[tid] = 0;
  __syncthreads();
  for (int i = tid; i < m; i += 256){
    unsigned rec = buf[(size_t)b*CAPB + i];
    recs[i] = rec;
    atomicAdd(&cnt[rec >> 17], 1);
  }
  __syncthreads();
  const int base = s_base;
  int v = (tid < NPB) ? cnt[tid] : 0;
  sc[tid] = v; __syncthreads();
  for (int off = 1; off < 256; off <<= 1){
    int a = (tid >= off) ? sc[tid - off] : 0;
    __syncthreads();
    sc[tid] += a;
    __syncthreads();
  }
  if (tid < NPB){
    int excl = sc[tid] - v;
    ex[tid] = excl;
    int g = b*NPB + tid;
    if (g < N){
      nspan[g] = make_int2(base + excl, v);
      dinv[g]  = rsqrtf((float)v + 1.0f);     // +1 self-loop
    }
  }
  __syncthreads();
  for (int i = tid; i < m; i += 256){
    unsigned rec = recs[i];
    int pos = base + atomicAdd(&ex[rec >> 17], 1);
    srcl[pos] = (int)(rec & 0x1FFFFu);
  }
}

// ---- GEMM: [nrows,128] @ [128,NCOL]; 128-row tile/block, 4 waves x 32 rows ----
template<int NCOL, bool A_F32, bool BIAS, bool RELU, bool SCALE, bool OUT_F32>
__global__ __launch_bounds__(256) void k_mm(const void* __restrict__ Ap,
    const unsigned short* __restrict__ Bf, const float* __restrict__ bias,
    const float* __restrict__ dinv, void* __restrict__ Cp, int nrows)
{
  constexpr int NCB = NCOL/16;
  const int tid = threadIdx.x;
  const int wave = tid >> 6, l = tid & 63;
  const int lr = l & 15, lg = l >> 4;
  const int row0 = blockIdx.x*128 + wave*32;

  f32x4 acc[2][NCB];
#pragma unroll
  for (int i = 0; i < 2; ++i)
#pragma unroll
    for (int j = 0; j < NCB; ++j) acc[i][j] = f32x4{0.f, 0.f, 0.f, 0.f};

  const int r0 = row0 + lr, r1 = row0 + 16 + lr;
  const bool ok0 = r0 < nrows, ok1 = r1 < nrows;

#pragma unroll
  for (int ks = 0; ks < 4; ++ks){
    const int kbase = ks*32 + lg*8;
    short8 a0 = short8{0,0,0,0,0,0,0,0}, a1 = short8{0,0,0,0,0,0,0,0};
    if constexpr (A_F32){
      const float* A = (const float*)Ap;
      if (ok0){
        const float* p = A + (size_t)r0*128 + kbase;
        f32x4 x0 = *(const f32x4*)p, x1 = *(const f32x4*)(p + 4);
#pragma unroll
        for (int j = 0; j < 4; ++j){ a0[j] = (short)f2bf(x0[j]); a0[j+4] = (short)f2bf(x1[j]); }
      }
      if (ok1){
        const float* p = A + (size_t)r1*128 + kbase;
        f32x4 x0 = *(const f32x4*)p, x1 = *(const f32x4*)(p + 4);
#pragma unroll
        for (int j = 0; j < 4; ++j){ a1[j] = (short)f2bf(x0[j]); a1[j+4] = (short)f2bf(x1[j]); }
      }
    } else {
      const unsigned short* A = (const unsigned short*)Ap;
      if (ok0) a0 = *(const short8*)(A + (size_t)r0*128 + kbase);
      if (ok1) a1 = *(const short8*)(A + (size_t)r1*128 + kbase);
    }
#pragma unroll
    for (int cb = 0; cb < NCB; ++cb){
      short8 b = *(const short8*)(Bf + ((size_t)(cb*4 + ks)*64 + l)*8);
      acc[0][cb] = __builtin_amdgcn_mfma_f32_16x16x32_bf16(a0, b, acc[0][cb], 0, 0, 0);
      acc[1][cb] = __builtin_amdgcn_mfma_f32_16x16x32_bf16(a1, b, acc[1][cb], 0, 0, 0);
    }
  }

  // C/D layout: col = lane&15, row = (lane>>4)*4 + reg
#pragma unroll
  for (int rb = 0; rb < 2; ++rb){
#pragma unroll
    for (int j = 0; j < 4; ++j){
      const int r = row0 + rb*16 + lg*4 + j;
      if (r >= nrows) continue;
      const float dv = SCALE ? dinv[r] : 1.0f;
#pragma unroll
      for (int cb = 0; cb < NCB; ++cb){
        const int c = cb*16 + lr;
        float v = acc[rb][cb][j];
        if constexpr (BIAS) v += bias[c];
        if constexpr (RELU) v = fmaxf(v, 0.0f);
        if constexpr (SCALE) v *= dv;
        if constexpr (OUT_F32) ((float*)Cp)[(size_t)r*NCOL + c] = v;
        else ((unsigned short*)Cp)[(size_t)r*NCOL + c] = f2bf(v);
      }
    }
  }
}

// ---- aggregation: one wave per node; readlane (SGPR) gather addressing ----
__global__ __launch_bounds__(256, 8) void k_agg(const unsigned* __restrict__ t,
    const int2* __restrict__ nspan, const int* __restrict__ srcl,
    const float* __restrict__ dinv, const float* __restrict__ bias,
    unsigned* __restrict__ hout, int n)
{
  const int node = blockIdx.x*4 + (threadIdx.x >> 6);
  if (node >= n) return;
  const int l = threadIdx.x & 63;

  const int2 sp = nspan[node];
  int i = sp.x;
  const int e = sp.x + sp.y;

  unsigned v = t[(size_t)node*64 + l];                 // self-loop term
  float a0 = bfLO(v), a1 = bfHI(v);

  int idx = (i < e) ? srcl[min(i + l, e - 1)] : 0;     // current 64-index chunk
  while (i < e){
    const int cnt = min(e - i, 64);
    const int nexti = i + cnt;
    const int idxn = (nexti < e) ? srcl[min(nexti + l, e - 1)] : 0;  // prefetch next chunk
    int j = 0;
    for (; j + 16 <= cnt; j += 16){
      unsigned u[16];
#pragma unroll
      for (int q = 0; q < 16; ++q){
        int s = __builtin_amdgcn_readlane(idx, j + q);
        u[q] = t[(size_t)s*64 + l];
      }
#pragma unroll
      for (int q = 0; q < 16; ++q){ a0 += bfLO(u[q]); a1 += bfHI(u[q]); }
    }
    for (; j + 8 <= cnt; j += 8){
      unsigned u[8];
#pragma unroll
      for (int q = 0; q < 8; ++q){
        int s = __builtin_amdgcn_readlane(idx, j + q);
        u[q] = t[(size_t)s*64 + l];
      }
#pragma unroll
      for (int q = 0; q < 8; ++q){ a0 += bfLO(u[q]); a1 += bfHI(u[q]); }
    }
    for (; j + 4 <= cnt; j += 4){
      unsigned u[4];
#pragma unroll
      for (int q = 0; q < 4; ++q){
        int s = __builtin_amdgcn_readlane(idx, j + q);
        u[q] = t[(size_t)s*64 + l];
      }
#pragma unroll
      for (int q = 0; q < 4; ++q){ a0 += bfLO(u[q]); a1 += bfHI(u[q]); }
    }
    for (; j < cnt; ++j){
      int s = __builtin_amdgcn_readlane(idx, j);
      unsigned u0 = t[(size_t)s*64 + l];
      a0 += bfLO(u0); a1 += bfHI(u0);
    }
    i = nexti; idx = idxn;
  }
  const float d = dinv[node];
  float o0 = fmaxf(fmaf(d, a0, bias[2*l]),     0.0f);
  float o1 = fmaxf(fmaf(d, a1, bias[2*l + 1]), 0.0f);
  hout[(size_t)node*64 + l] = (unsigned)f2bf(o0) | ((unsigned)f2bf(o1) << 16);
}

extern "C" void kernel_launch(void* const* d_in, const int* in_sizes, int n_in,
                              void* d_out, int out_size, void* d_ws, size_t ws_size,
                              hipStream_t stream)
{
  const float* x     = (const float*)d_in[0];
  const void*  ei    = d_in[1];
  const float* W_in  = (const float*)d_in[2];
  const float* b_in  = (const float*)d_in[3];
  const float* convW = (const float*)d_in[4];
  const float* convb = (const float*)d_in[5];
  const float* W_out = (const float*)d_in[6];
  const float* b_out = (const float*)d_in[7];
  float* out = (float*)d_out;

  const int N = in_sizes[0] / 128;
  const int E = in_sizes[1] / 2;
  const int NBUCK = (N + NPB - 1) / NPB;

  char* w = (char*)d_ws;
  auto alloc = [&](size_t b){ char* p = w; w += (b + 255) & ~(size_t)255; return p; };
  unsigned short* h    = (unsigned short*)alloc((size_t)N*128*2);
  unsigned short* t    = (unsigned short*)alloc((size_t)N*128*2);
  unsigned short* Bf   = (unsigned short*)alloc((size_t)5*16384*2);
  float* dinv          = (float*)alloc((size_t)N*4);
  int2* nspan          = (int2*)alloc((size_t)N*8);
  int* srcl            = (int*)alloc((size_t)E*4);
  int* bcnt            = (int*)alloc((size_t)(NBUCK*16 + 16)*4);   // + cursor tail
  unsigned* bbuf       = (unsigned*)t;     // alias: bucket buffer dead before t is live

  int* cursor = bcnt + NBUCK*16;
  const int zeroN = NBUCK*16 + 16;
  const int ZB = (zeroN + 255)/256;
  const int MB = (N + 127) / 128;

  k_wprep_all<<<40 + ZB, 256, 0, stream>>>(W_in, convW, W_out, Bf, bcnt, zeroN);
  k_bucket2<<<(E + TILE - 1)/TILE, 256, 0, stream>>>(ei, bcnt, bbuf, E, NBUCK);
  k_csr2  <<<NBUCK, 256, 0, stream>>>(bcnt, bbuf, nspan, srcl, dinv, cursor, N);

  // h = relu(x @ W_in + b_in)
  k_mm<128, true, true, true, false, false><<<MB, 256, 0, stream>>>(x, Bf, b_in, nullptr, h, N);

  for (int L = 0; L < 3; ++L){
    // t = dinv[r] * (h @ conv_W[L])
    k_mm<128, false, false, false, true, false><<<MB, 256, 0, stream>>>(h, Bf + (size_t)(1+L)*16384, nullptr, dinv, t, N);
    // h = relu(dinv[c] * (sum_in t + t[c]) + b)
    k_agg<<<(N + 3)/4, 256, 0, stream>>>((const unsigned*)t, nspan, srcl, dinv,
                                         convb + (size_t)L*128, (unsigned*)h, N);
  }

  // logits = h @ W_out + b_out  (f32 out)
  k_mm<64, false, true, false, false, true><<<MB, 256, 0, stream>>>(h, Bf + (size_t)4*16384, b_out, nullptr, out, N);
}